// Round 18
// baseline (118.999 us; speedup 1.0000x reference)
//
#include <hip/hip_runtime.h>
#include <hip/hip_bf16.h>

#define BB 4      // batch
#define SS 1023   // source length = 2T-1
#define TT 512    // window length
#define CC 1024   // embed dim
#define DD 64     // head size
#define NROW (BB*SS)    // 4092
#define NROWP 4096      // padded kT row stride: kT[d][b*1024 + s]

typedef float f4 __attribute__((ext_vector_type(4)));
typedef float f2 __attribute__((ext_vector_type(2)));
typedef short bf16x8 __attribute__((ext_vector_type(8)));
typedef float f32x4 __attribute__((ext_vector_type(4)));

// RTN bf16 split: v ~= hi + lo (packed u32 lo<<16|hi).
// SESSION INVARIANT: this split + ALL FOUR MFMA products is the only
// verified-passing config (0.0156). Manual trunc/half-up splits with al*bl
// dropped fail deterministically at ~0.18 (r14/r15/r16). Do not re-optimize.
__device__ __forceinline__ unsigned split_rtn(float v) {
    const unsigned u  = __builtin_bit_cast(unsigned, v);
    const unsigned r  = u + 0x7FFFu + ((u >> 16) & 1u);
    const unsigned hi = r >> 16;
    const float hif   = __builtin_bit_cast(float, r & 0xFFFF0000u);
    const float res   = v - hif;
    const unsigned u2 = __builtin_bit_cast(unsigned, res);
    const unsigned r2 = u2 + 0x7FFFu + ((u2 >> 16) & 1u);
    return (r2 & 0xFFFF0000u) | hi;                    // lo<<16 | hi
}

// ---------------------------------------------------------------------------
// Kernel 1: split W{k,v,q} into B-fragment-ordered bf16 hi/lo (RTN). (proven)
// ---------------------------------------------------------------------------
__global__ __launch_bounds__(64) void wsplit_kernel(
    const float* __restrict__ Wk,
    const float* __restrict__ Wv,
    const float* __restrict__ Wq,
    unsigned short* __restrict__ bwh,
    unsigned short* __restrict__ bwl)
{
    const int f    = blockIdx.x;        // 0..383
    const int p    = f >> 7;
    const int rem  = f & 127;
    const int nsub = rem >> 5;
    const int ks   = rem & 31;
    const int lane = threadIdx.x;
    const int quad = lane >> 4, l4 = lane & 15;
    const float* W = (p == 0) ? Wk : (p == 1) ? Wv : Wq;
    const int n = nsub * 16 + l4;

    bf16x8 h, l;
#pragma unroll
    for (int j = 0; j < 8; ++j) {
        const int k = ks * 32 + quad * 8 + j;
        const unsigned hl = split_rtn(W[k * DD + n]);
        h[j] = (short)(hl & 0xFFFFu);
        l[j] = (short)(hl >> 16);
    }
    ((bf16x8*)bwh)[f * 64 + lane] = h;
    ((bf16x8*)bwl)[f * 64 + lane] = l;
}

// ---------------------------------------------------------------------------
// Kernel 2: projections via MFMA 16x16x32 bf16 — r17 passing version
// VERBATIM (in-register split_rtn, full 8-MFMA product set, padded kT).
// ---------------------------------------------------------------------------
__global__ __launch_bounds__(64) void proj_mfma_kernel(
    const float* __restrict__ x,
    const unsigned short* __restrict__ bwh,
    const unsigned short* __restrict__ bwl,
    float* __restrict__ kT,     // [DD][NROWP] padded
    float* __restrict__ vbuf,   // [NROW][DD]
    float* __restrict__ qbuf)   // [BB*TT][DD]
{
    const int blk  = blockIdx.x;        // 0..1535
    const int nh   = blk & 1;
    const int pm   = blk >> 1;          // 0..767
    const int p    = pm % 3;
    const int mt   = pm / 3;            // 0..255
    const int bs0  = mt * 16;
    const int lane = threadIdx.x;
    const int quad = lane >> 4, l4 = lane & 15;
    const int nsub0 = nh * 2;

    int arow = bs0 + l4; if (arow > NROW - 1) arow = NROW - 1;   // pad clamp
    const float* ap = x + (size_t)arow * CC;
    const bf16x8* bh = (const bf16x8*)bwh
                     + (size_t)((p * 4 + nsub0) * 32) * 64 + lane;
    const bf16x8* bl = (const bf16x8*)bwl
                     + (size_t)((p * 4 + nsub0) * 32) * 64 + lane;

    f32x4 acc0 = {0.f,0.f,0.f,0.f}, acc1 = {0.f,0.f,0.f,0.f};

#pragma unroll 4
    for (int ks = 0; ks < 32; ++ks) {
        const int k0 = ks * 32 + quad * 8;
        const f4 xa = *(const f4*)(ap + k0);
        const f4 xb = *(const f4*)(ap + k0 + 4);
        bf16x8 ah, al;
#pragma unroll
        for (int j = 0; j < 4; ++j) {
            const unsigned hl = split_rtn(xa[j]);
            ah[j] = (short)(hl & 0xFFFFu);
            al[j] = (short)(hl >> 16);
        }
#pragma unroll
        for (int j = 0; j < 4; ++j) {
            const unsigned hl = split_rtn(xb[j]);
            ah[4 + j] = (short)(hl & 0xFFFFu);
            al[4 + j] = (short)(hl >> 16);
        }
        const bf16x8 bh0 = bh[(0 * 32 + ks) * 64];
        const bf16x8 bh1 = bh[(1 * 32 + ks) * 64];
        const bf16x8 bl0 = bl[(0 * 32 + ks) * 64];
        const bf16x8 bl1 = bl[(1 * 32 + ks) * 64];

        acc0 = __builtin_amdgcn_mfma_f32_16x16x32_bf16(ah, bh0, acc0, 0, 0, 0);
        acc1 = __builtin_amdgcn_mfma_f32_16x16x32_bf16(ah, bh1, acc1, 0, 0, 0);
        acc0 = __builtin_amdgcn_mfma_f32_16x16x32_bf16(ah, bl0, acc0, 0, 0, 0);
        acc1 = __builtin_amdgcn_mfma_f32_16x16x32_bf16(ah, bl1, acc1, 0, 0, 0);
        acc0 = __builtin_amdgcn_mfma_f32_16x16x32_bf16(al, bh0, acc0, 0, 0, 0);
        acc1 = __builtin_amdgcn_mfma_f32_16x16x32_bf16(al, bh1, acc1, 0, 0, 0);
        acc0 = __builtin_amdgcn_mfma_f32_16x16x32_bf16(al, bl0, acc0, 0, 0, 0);
        acc1 = __builtin_amdgcn_mfma_f32_16x16x32_bf16(al, bl1, acc1, 0, 0, 0);
    }

    // ---- epilogue: D[row=quad*4+reg][col=l4], d = nsub*16 + l4 ----
#pragma unroll
    for (int s = 0; s < 2; ++s) {
        const f32x4 a = s ? acc1 : acc0;
        const int d = (nsub0 + s) * 16 + l4;
#pragma unroll
        for (int reg = 0; reg < 4; ++reg) {
            const int bs = bs0 + quad * 4 + reg;
            if (bs < NROW) {
                const float val = a[reg];
                const int b = bs / SS, ss = bs - b * SS;
                if (p == 0) {
                    kT[(size_t)d * NROWP + b * 1024 + ss] = val;   // padded
                } else if (p == 1) {
                    vbuf[(size_t)bs * DD + d] = val;
                } else {
                    if (ss >= TT - 1)
                        qbuf[((size_t)b * TT + (ss - (TT - 1))) * DD + d] = val;
                }
            }
        }
    }
}

// ---------------------------------------------------------------------------
// Kernel 3: attention, WT=2 windows/block, 1024 blocks x 512 threads.
// qbias kernel ELIMINATED: bias folded into phase 1 per-iter (1 extra
// coalesced f2 load + 4 adds) — removes a graph node + 8 MB qb round-trip.
// Phase 1: thread (h=tid>>8, p=tid&255) computes 4 logits (t=2p,2p+1 x
// m=0,1) over dd in [32h,32h+32): logit[m][t] = sum_d q[m][d]*(k[w0+m+t][d]
// + bias[d][t]). Partials combined across h in LDS part[h][m][t].
// Softmax: wave wv -> row m=wv>>2, quarter wv&3. Phase 2: sliding v register.
// ---------------------------------------------------------------------------
__global__ __launch_bounds__(512) void attn_kernel(
    const float* __restrict__ kT,     // [DD][NROWP] padded
    const float* __restrict__ vbuf,   // [NROW][DD]
    const float* __restrict__ qbuf,   // [BB*TT][DD]
    const float* __restrict__ bias,   // [DD][TT]
    float* __restrict__ out)          // [BB*TT][DD]
{
    __shared__ __align__(8) float qsT[DD][2];        // [d][m]
    __shared__ __align__(8) float part[2][2][TT];    // [h][m][t]  8 KB
    __shared__ __align__(8) float weiT[TT][2];       // [t][m]     4 KB
    __shared__ float red[16];
    __shared__ float invs[2];
    __shared__ float partial[8][2][DD];              // 4 KB

    const int tid  = threadIdx.x;
    const int lane = tid & 63;
    const int wv   = tid >> 6;          // 0..7
    const int blk  = blockIdx.x;        // 0..1023
    const int b    = blk >> 8;
    const int w0   = (blk & 255) * 2;

    if (tid < 2 * DD) {
        const int m = tid >> 6, dd = tid & 63;
        qsT[dd][m] = qbuf[((size_t)b * TT + w0 + m) * DD + dd];
    }
    __syncthreads();

    // ---- phase 1 ----
    {
        const int h = tid >> 8, p = tid & 255;
        const int t0 = 2 * p;
        const float* kcol = kT + (size_t)(32 * h) * NROWP + b * 1024 + w0 + t0;
        const float* bcol = bias + (32 * h) * TT + t0;
        float a00 = 0.f, a01 = 0.f, a10 = 0.f, a11 = 0.f;   // a[m][jt]
#pragma unroll 8
        for (int i = 0; i < 32; ++i) {
            const int dd = 32 * h + i;
            const float* kr = kcol + (size_t)i * NROWP;
            const f2 kA = *(const f2*)kr;         // k[w0+t0], k[w0+t0+1]
            const f2 kB = *(const f2*)(kr + 2);   // k[w0+t0+2]
            const f2 bb = *(const f2*)(bcol + i * TT);   // bias[dd][t0..t0+1]
            const float q0 = qsT[dd][0], q1 = qsT[dd][1];
            a00 = fmaf(q0, kA[0] + bb[0], a00);
            a01 = fmaf(q0, kA[1] + bb[1], a01);
            a10 = fmaf(q1, kA[1] + bb[0], a10);
            a11 = fmaf(q1, kB[0] + bb[1], a11);
        }
        *(f2*)&part[h][0][t0] = (f2){a00, a01};
        *(f2*)&part[h][1][t0] = (f2){a10, a11};
    }
    __syncthreads();

    // ---- softmax: wave wv -> row m = wv>>2, quarter qt = wv&3 ----
    {
        const int m = wv >> 2, qt = wv & 3;
        const int tb = qt * 128 + lane;
        float r0 = part[0][m][tb]      + part[1][m][tb];
        float r1 = part[0][m][tb + 64] + part[1][m][tb + 64];
        float mx = fmaxf(r0, r1);
#pragma unroll
        for (int off = 1; off < 64; off <<= 1)
            mx = fmaxf(mx, __shfl_xor(mx, off, 64));
        if (lane == 0) red[wv] = mx;
        __syncthreads();
        mx = fmaxf(fmaxf(red[m * 4], red[m * 4 + 1]),
                   fmaxf(red[m * 4 + 2], red[m * 4 + 3]));
        const float e0 = __expf(r0 - mx), e1 = __expf(r1 - mx);
        weiT[tb][m] = e0;
        weiT[tb + 64][m] = e1;
        float sum = e0 + e1;
#pragma unroll
        for (int off = 1; off < 64; off <<= 1)
            sum += __shfl_xor(sum, off, 64);
        if (lane == 0) red[8 + wv] = sum;
        __syncthreads();
        if (tid < 2)
            invs[tid] = 1.f / (red[8 + tid * 4] + red[9 + tid * 4] +
                               red[10 + tid * 4] + red[11 + tid * 4]);
    }
    __syncthreads();

    // ---- phase 2: PV, wave wv covers 64 t, sliding v register ----
    {
        const int t0r = wv * 64;
        const float* vb = vbuf + ((size_t)b * SS + w0 + t0r) * DD + lane;
        float p0 = 0.f, p1 = 0.f;
        float v0 = vb[0];
#pragma unroll 4
        for (int t = 0; t < 64; ++t) {
            const float v1 = vb[(size_t)(t + 1) * DD];
            const f2 w2 = *(const f2*)&weiT[t0r + t][0];
            p0 = fmaf(w2[0], v0, p0);
            p1 = fmaf(w2[1], v1, p1);
            v0 = v1;
        }
        partial[wv][0][lane] = p0;
        partial[wv][1][lane] = p1;
    }
    __syncthreads();

    // ---- final reduce + store ----
    if (tid < 2 * DD) {
        const int m = tid >> 6, dd = tid & 63;
        float o = 0.f;
#pragma unroll
        for (int j = 0; j < 8; ++j) o += partial[j][m][dd];
        out[((size_t)b * TT + w0 + m) * DD + dd] = o * invs[m];
    }
}

// ---------------------------------------------------------------------------
extern "C" void kernel_launch(void* const* d_in, const int* in_sizes, int n_in,
                              void* d_out, int out_size, void* d_ws, size_t ws_size,
                              hipStream_t stream) {
    const float* x    = (const float*)d_in[0];
    const float* Wk   = (const float*)d_in[1];
    const float* Wv   = (const float*)d_in[2];
    const float* Wq   = (const float*)d_in[3];
    const float* bias = (const float*)d_in[4];
    float* out = (float*)d_out;

    char* ws = (char*)d_ws;
    float* kT             = (float*)(ws + 0);                 // DD*4096*4 = 1 MB
    float* vbuf           = (float*)(ws + (2u  << 20));       // 1.05 MB
    float* qbuf           = (float*)(ws + (4u  << 20));       // 0.52 MB
    unsigned short* bwh   = (unsigned short*)(ws + (16u << 20));  // 0.39 MB
    unsigned short* bwl   = (unsigned short*)(ws + (20u << 20));  // 0.39 MB

    wsplit_kernel<<<384, 64, 0, stream>>>(Wk, Wv, Wq, bwh, bwl);
    proj_mfma_kernel<<<1536, 64, 0, stream>>>(x, bwh, bwl, kT, vbuf, qbuf);
    attn_kernel<<<BB * TT / 2, 512, 0, stream>>>(kT, vbuf, qbuf, bias, out);
}